// Round 1
// baseline (1232.390 us; speedup 1.0000x reference)
//
#include <hip/hip_runtime.h>
#include <math.h>

#define B_   8
#define NQ_  900
#define D_   256
#define H_   8
#define P_   4
#define BEV_ 200
#define FFN_ 512
#define HD_  32

// ---------------------------------------------------------------------------
// LayerNorm over last dim (256), optional element-wise pos add before norm.
// One wave (64 lanes) per row; 4 rows per 256-thread block.
// ---------------------------------------------------------------------------
__global__ __launch_bounds__(256)
void ln_kernel(const float* __restrict__ x, const float* __restrict__ pos,
               const float* __restrict__ gamma, const float* __restrict__ beta,
               float* __restrict__ out, int rows)
{
    int w    = threadIdx.x >> 6;
    int lane = threadIdx.x & 63;
    int row  = blockIdx.x * 4 + w;
    if (row >= rows) return;
    size_t base = (size_t)row * D_ + lane * 4;
    float4 v = *(const float4*)(x + base);
    if (pos) {
        float4 p = *(const float4*)(pos + base);
        v.x += p.x; v.y += p.y; v.z += p.z; v.w += p.w;
    }
    float s = v.x + v.y + v.z + v.w;
    float q = v.x*v.x + v.y*v.y + v.z*v.z + v.w*v.w;
    #pragma unroll
    for (int o = 1; o < 64; o <<= 1) {
        s += __shfl_xor(s, o, 64);
        q += __shfl_xor(q, o, 64);
    }
    float m   = s * (1.0f / D_);
    float var = q * (1.0f / D_) - m * m;
    float inv = rsqrtf(var + 1e-5f);
    float4 g = *(const float4*)(gamma + lane * 4);
    float4 b = *(const float4*)(beta  + lane * 4);
    float4 o4;
    o4.x = (v.x - m) * inv * g.x + b.x;
    o4.y = (v.y - m) * inv * g.y + b.y;
    o4.z = (v.z - m) * inv * g.z + b.z;
    o4.w = (v.w - m) * inv * g.w + b.w;
    *(float4*)(out + base) = o4;
}

// ---------------------------------------------------------------------------
// Tiled fp32 GEMM: C[m,n] = sum_k A[m,k] * W[n,k] + bias[n] (+res) (relu)
// 128x128 tile, BK=16, 256 threads, 8x8 per thread (split 4+4 at +64).
// ---------------------------------------------------------------------------
#define BM 128
#define BN 128
#define BKK 16

template<int RELU>
__global__ __launch_bounds__(256)
void gemm_kernel(const float* __restrict__ A, const float* __restrict__ W,
                 const float* __restrict__ bias, const float* res,
                 float* C, int M, int N, int K)
{
    __shared__ __align__(16) float As[BKK][BM + 4];
    __shared__ __align__(16) float Ws[BKK][BN + 4];
    const int t  = threadIdx.x;
    const int m0 = blockIdx.y * BM;
    const int n0 = blockIdx.x * BN;
    const int tx = t & 15, ty = t >> 4;
    float acc[8][8];
    #pragma unroll
    for (int i = 0; i < 8; ++i)
        #pragma unroll
        for (int j = 0; j < 8; ++j) acc[i][j] = 0.f;

    const int lr = t >> 1;        // 0..127
    const int lk = (t & 1) * 8;   // 0 or 8

    for (int k0 = 0; k0 < K; k0 += BKK) {
        {
            int gm = m0 + lr;
            float4 v0 = make_float4(0.f,0.f,0.f,0.f), v1 = v0;
            if (gm < M) {
                const float* src = A + (size_t)gm * K + k0 + lk;
                v0 = *(const float4*)src;
                v1 = *(const float4*)(src + 4);
            }
            As[lk+0][lr] = v0.x; As[lk+1][lr] = v0.y; As[lk+2][lr] = v0.z; As[lk+3][lr] = v0.w;
            As[lk+4][lr] = v1.x; As[lk+5][lr] = v1.y; As[lk+6][lr] = v1.z; As[lk+7][lr] = v1.w;
        }
        {
            int gn = n0 + lr;
            float4 v0 = make_float4(0.f,0.f,0.f,0.f), v1 = v0;
            if (gn < N) {
                const float* src = W + (size_t)gn * K + k0 + lk;
                v0 = *(const float4*)src;
                v1 = *(const float4*)(src + 4);
            }
            Ws[lk+0][lr] = v0.x; Ws[lk+1][lr] = v0.y; Ws[lk+2][lr] = v0.z; Ws[lk+3][lr] = v0.w;
            Ws[lk+4][lr] = v1.x; Ws[lk+5][lr] = v1.y; Ws[lk+6][lr] = v1.z; Ws[lk+7][lr] = v1.w;
        }
        __syncthreads();
        #pragma unroll
        for (int k = 0; k < BKK; ++k) {
            float4 a0 = *(const float4*)&As[k][ty*4];
            float4 a1 = *(const float4*)&As[k][ty*4 + 64];
            float4 w0 = *(const float4*)&Ws[k][tx*4];
            float4 w1 = *(const float4*)&Ws[k][tx*4 + 64];
            float am[8] = {a0.x,a0.y,a0.z,a0.w,a1.x,a1.y,a1.z,a1.w};
            float wn[8] = {w0.x,w0.y,w0.z,w0.w,w1.x,w1.y,w1.z,w1.w};
            #pragma unroll
            for (int i = 0; i < 8; ++i)
                #pragma unroll
                for (int j = 0; j < 8; ++j)
                    acc[i][j] = fmaf(am[i], wn[j], acc[i][j]);
        }
        __syncthreads();
    }
    #pragma unroll
    for (int i = 0; i < 8; ++i) {
        int m = m0 + (i < 4 ? ty*4 + i : 64 + ty*4 + (i - 4));
        if (m >= M) continue;
        #pragma unroll
        for (int jc = 0; jc < 2; ++jc) {
            int n = n0 + tx*4 + jc*64;
            if (n >= N) continue;
            float4 bv = *(const float4*)(bias + n);
            float r0 = acc[i][jc*4+0] + bv.x;
            float r1 = acc[i][jc*4+1] + bv.y;
            float r2 = acc[i][jc*4+2] + bv.z;
            float r3 = acc[i][jc*4+3] + bv.w;
            if (res) {
                float4 rv = *(const float4*)(res + (size_t)m * N + n);
                r0 += rv.x; r1 += rv.y; r2 += rv.z; r3 += rv.w;
            }
            if (RELU) {
                r0 = fmaxf(r0, 0.f); r1 = fmaxf(r1, 0.f);
                r2 = fmaxf(r2, 0.f); r3 = fmaxf(r3, 0.f);
            }
            *(float4*)(C + (size_t)m * N + n) = make_float4(r0, r1, r2, r3);
        }
    }
}

// ---------------------------------------------------------------------------
// Self-attention: one block per (b,h,q-tile of 4). Two-pass softmax in LDS.
// qkv layout: [B,NQ,768] with q @0, k @256, v @512 (head h at h*32).
// ---------------------------------------------------------------------------
__global__ __launch_bounds__(256)
void attn_kernel(const float* __restrict__ qkv, float* __restrict__ out)
{
    __shared__ float sq[4][HD_];
    __shared__ float sp[4][NQ_];
    __shared__ float sred[32][4][HD_];
    __shared__ float sinv[4];
    const int t  = threadIdx.x;
    const int b  = blockIdx.y >> 3;
    const int h  = blockIdx.y & 7;
    const int q0 = blockIdx.x * 4;   // 900 = 225*4, no remainder

    if (t < 128) {
        int qi = t >> 5, c = t & 31;
        sq[qi][c] = qkv[((size_t)(b * NQ_ + q0 + qi)) * 768 + h * HD_ + c];
    }
    __syncthreads();
    const float scale = 0.17677669529663687f; // 1/sqrt(32)

    // phase 1: scores
    for (int k = t; k < NQ_; k += 256) {
        const float* kp = qkv + ((size_t)(b * NQ_ + k)) * 768 + D_ + h * HD_;
        float4 kr[8];
        #pragma unroll
        for (int c = 0; c < 8; ++c) kr[c] = *(const float4*)(kp + c * 4);
        #pragma unroll
        for (int qi = 0; qi < 4; ++qi) {
            const float4* sv = (const float4*)sq[qi];
            float dot = 0.f;
            #pragma unroll
            for (int c = 0; c < 8; ++c) {
                float4 qv = sv[c];
                dot += qv.x*kr[c].x + qv.y*kr[c].y + qv.z*kr[c].z + qv.w*kr[c].w;
            }
            sp[qi][k] = dot * scale;
        }
    }
    __syncthreads();

    // phase 2: softmax (4 groups of 64 lanes, one per q row)
    {
        int qi = t >> 6, lane = t & 63;
        float mx = -1e30f;
        for (int k = lane; k < NQ_; k += 64) mx = fmaxf(mx, sp[qi][k]);
        #pragma unroll
        for (int o = 1; o < 64; o <<= 1) mx = fmaxf(mx, __shfl_xor(mx, o, 64));
        float sum = 0.f;
        for (int k = lane; k < NQ_; k += 64) {
            float e = expf(sp[qi][k] - mx);
            sp[qi][k] = e;
            sum += e;
        }
        #pragma unroll
        for (int o = 1; o < 64; o <<= 1) sum += __shfl_xor(sum, o, 64);
        if (lane == 0) sinv[qi] = 1.f / sum;
    }
    __syncthreads();

    // phase 3: PV. 32 key-groups x 8 channel-groups(4ch each).
    {
        int g  = t >> 3;
        int dg = (t & 7) * 4;
        float acc[4][4];
        #pragma unroll
        for (int qi = 0; qi < 4; ++qi)
            #pragma unroll
            for (int c = 0; c < 4; ++c) acc[qi][c] = 0.f;
        for (int k = g; k < NQ_; k += 32) {
            const float* vp = qkv + ((size_t)(b * NQ_ + k)) * 768 + 2 * D_ + h * HD_ + dg;
            float4 v = *(const float4*)vp;
            #pragma unroll
            for (int qi = 0; qi < 4; ++qi) {
                float p = sp[qi][k];
                acc[qi][0] = fmaf(p, v.x, acc[qi][0]);
                acc[qi][1] = fmaf(p, v.y, acc[qi][1]);
                acc[qi][2] = fmaf(p, v.z, acc[qi][2]);
                acc[qi][3] = fmaf(p, v.w, acc[qi][3]);
            }
        }
        #pragma unroll
        for (int qi = 0; qi < 4; ++qi)
            #pragma unroll
            for (int c = 0; c < 4; ++c) sred[g][qi][dg + c] = acc[qi][c];
    }
    __syncthreads();
    if (t < 128) {
        int qi = t >> 5, d = t & 31;
        float o = 0.f;
        #pragma unroll
        for (int g = 0; g < 32; ++g) o += sred[g][qi][d];
        out[((size_t)(b * NQ_ + q0 + qi)) * D_ + h * HD_ + d] = o * sinv[qi];
    }
}

// ---------------------------------------------------------------------------
// Prep: tanh(offsets)*R + ref -> pixel coords; softmax over P=4 weights.
// One thread per (b,q,h). Stores gx4/gy4/w4 as float4 per bqh.
// ---------------------------------------------------------------------------
__global__ __launch_bounds__(256)
void prep_kernel(const float* __restrict__ off_raw, const float* __restrict__ wt_raw,
                 const float* __restrict__ refp,
                 float4* __restrict__ sx, float4* __restrict__ sy, float4* __restrict__ sw)
{
    int idx = blockIdx.x * 256 + threadIdx.x;
    if (idx >= B_ * NQ_ * H_) return;
    int h  = idx & 7;
    int bq = idx >> 3;
    const float* orow = off_raw + (size_t)bq * (H_ * P_ * 2) + h * 8;
    const float* wrow = wt_raw  + (size_t)bq * (H_ * P_)     + h * 4;
    float rx = refp[bq * 2 + 0];
    float ry = refp[bq * 2 + 1];
    float gx[4], gy[4], w[4];
    #pragma unroll
    for (int p = 0; p < 4; ++p) {
        float ox = tanhf(orow[p * 2 + 0]) * 0.2f;
        float oy = tanhf(orow[p * 2 + 1]) * 0.2f;
        // grid = loc*2-1; px = (grid+1)*100-0.5 = loc*200-0.5
        gx[p] = (rx + ox) * (float)BEV_ - 0.5f;
        gy[p] = (ry + oy) * (float)BEV_ - 0.5f;
        w[p]  = wrow[p];
    }
    float mx = fmaxf(fmaxf(w[0], w[1]), fmaxf(w[2], w[3]));
    float e0 = expf(w[0]-mx), e1 = expf(w[1]-mx), e2 = expf(w[2]-mx), e3 = expf(w[3]-mx);
    float inv = 1.f / (e0 + e1 + e2 + e3);
    sx[idx] = make_float4(gx[0], gx[1], gx[2], gx[3]);
    sy[idx] = make_float4(gy[0], gy[1], gy[2], gy[3]);
    sw[idx] = make_float4(e0*inv, e1*inv, e2*inv, e3*inv);
}

// ---------------------------------------------------------------------------
// Bilinear sampler + weighted sum over P. Thread per (b,q,h,d); consecutive
// d -> consecutive memory addresses (coalesced 128B per 32 lanes).
// memory: [B, 200*200, 256]; channel for (h,d) = h*32+d.
// ---------------------------------------------------------------------------
__global__ __launch_bounds__(256)
void sample_kernel(const float* __restrict__ mem,
                   const float4* __restrict__ sx, const float4* __restrict__ sy,
                   const float4* __restrict__ sw, float* __restrict__ fused)
{
    int tid = blockIdx.x * 256 + threadIdx.x;
    if (tid >= B_ * NQ_ * H_ * HD_) return;
    int d   = tid & 31;
    int bqh = tid >> 5;
    int h   = bqh & 7;
    int bq  = bqh >> 3;
    int b   = bq / NQ_;
    const float* mb = mem + (size_t)b * (BEV_ * BEV_) * D_ + h * HD_ + d;
    float4 X = sx[bqh], Y = sy[bqh], W = sw[bqh];
    float xs[4] = {X.x, X.y, X.z, X.w};
    float ys[4] = {Y.x, Y.y, Y.z, Y.w};
    float ws[4] = {W.x, W.y, W.z, W.w};
    float acc = 0.f;
    #pragma unroll
    for (int p = 0; p < 4; ++p) {
        float gx = xs[p], gy = ys[p];
        float x0f = floorf(gx), y0f = floorf(gy);
        int x0 = (int)x0f, y0 = (int)y0f;
        float wx1 = gx - x0f, wy1 = gy - y0f;
        float wx0 = 1.f - wx1, wy0 = 1.f - wy1;
        float s = 0.f;
        #pragma unroll
        for (int cy = 0; cy < 2; ++cy) {
            int yy = y0 + cy;
            if (yy < 0 || yy >= BEV_) continue;
            float wyv = cy ? wy1 : wy0;
            #pragma unroll
            for (int cx = 0; cx < 2; ++cx) {
                int xx = x0 + cx;
                if (xx < 0 || xx >= BEV_) continue;
                float wxv = cx ? wx1 : wx0;
                s += wyv * wxv * mb[((size_t)yy * BEV_ + xx) * D_];
            }
        }
        acc += ws[p] * s;
    }
    fused[(size_t)bq * D_ + h * HD_ + d] = acc;
}

// ---------------------------------------------------------------------------
extern "C" void kernel_launch(void* const* d_in, const int* in_sizes, int n_in,
                              void* d_out, int out_size, void* d_ws, size_t ws_size,
                              hipStream_t stream) {
    const float* query     = (const float*)d_in[0];
    const float* memory    = (const float*)d_in[1];
    const float* refp      = (const float*)d_in[2];
    const float* query_pos = (const float*)d_in[3];
    const float* in_w  = (const float*)d_in[4];
    const float* in_b  = (const float*)d_in[5];
    const float* out_w = (const float*)d_in[6];
    const float* out_b = (const float*)d_in[7];
    const float* off_w = (const float*)d_in[8];
    const float* off_b = (const float*)d_in[9];
    const float* wt_w  = (const float*)d_in[10];
    const float* wt_b  = (const float*)d_in[11];
    const float* co_w  = (const float*)d_in[12];
    const float* co_b  = (const float*)d_in[13];
    const float* f_w1  = (const float*)d_in[14];
    const float* f_b1  = (const float*)d_in[15];
    const float* f_w2  = (const float*)d_in[16];
    const float* f_b2  = (const float*)d_in[17];
    const float* n1s = (const float*)d_in[18];
    const float* n1b = (const float*)d_in[19];
    const float* n2s = (const float*)d_in[20];
    const float* n2b = (const float*)d_in[21];
    const float* n3s = (const float*)d_in[22];
    const float* n3b = (const float*)d_in[23];
    float* outp = (float*)d_out;

    const int M = B_ * NQ_; // 7200
    float* ws      = (float*)d_ws;
    float* buf_ln  = ws;                       // 7200*256
    float* buf_qkv = buf_ln  + (size_t)M * 768 / 3 * 1 + (1843200 - M * 256); // keep simple below
    // explicit layout:
    buf_ln  = ws;                              // 1,843,200 floats
    buf_qkv = ws + 1843200;                    // 5,529,600 floats
    float* buf_tmp = buf_qkv + 5529600;        // 1,843,200 floats
    float* buf_q1  = buf_tmp + 1843200;        // 1,843,200 floats
    float* samp    = buf_q1  + 1843200;        //   691,200 floats
    float* off_raw = buf_qkv;                  // 7200*64 (reuses qkv buffer)
    float* wt_raw  = buf_qkv + (size_t)M * 64; // 7200*32
    float* h1      = buf_qkv;                  // 7200*512 (reuses qkv buffer)

    dim3 blk(256);

    // 1. LN1(query + query_pos)
    ln_kernel<<<dim3(M / 4), blk, 0, stream>>>(query, query_pos, n1s, n1b, buf_ln, M);
    // 2. QKV projection [7200,768]
    gemm_kernel<0><<<dim3(6, 57), blk, 0, stream>>>(buf_ln, in_w, in_b, nullptr, buf_qkv, M, 768, 256);
    // 3. self-attention -> buf_tmp [7200,256]
    attn_kernel<<<dim3(225, B_ * H_), blk, 0, stream>>>(buf_qkv, buf_tmp);
    // 4. out proj + residual(query) -> buf_q1
    gemm_kernel<0><<<dim3(2, 57), blk, 0, stream>>>(buf_tmp, out_w, out_b, query, buf_q1, M, 256, 256);
    // 5. LN2(q1 + query_pos)
    ln_kernel<<<dim3(M / 4), blk, 0, stream>>>(buf_q1, query_pos, n2s, n2b, buf_ln, M);
    // 6. offsets / weights projections
    gemm_kernel<0><<<dim3(1, 57), blk, 0, stream>>>(buf_ln, off_w, off_b, nullptr, off_raw, M, 64, 256);
    gemm_kernel<0><<<dim3(1, 57), blk, 0, stream>>>(buf_ln, wt_w, wt_b, nullptr, wt_raw, M, 32, 256);
    // 7. prep sampling coords + softmax weights
    prep_kernel<<<dim3((B_ * NQ_ * H_ + 255) / 256), blk, 0, stream>>>(
        off_raw, wt_raw, refp,
        (float4*)samp, (float4*)samp + B_ * NQ_ * H_, (float4*)samp + 2 * B_ * NQ_ * H_);
    // 8. bilinear sample + fuse -> buf_tmp [7200,256]
    sample_kernel<<<dim3(B_ * NQ_ * H_ * HD_ / 256), blk, 0, stream>>>(
        memory, (const float4*)samp, (const float4*)samp + B_ * NQ_ * H_,
        (const float4*)samp + 2 * B_ * NQ_ * H_, buf_tmp);
    // 9. co proj + residual(q1) -> d_out (query2)
    gemm_kernel<0><<<dim3(2, 57), blk, 0, stream>>>(buf_tmp, co_w, co_b, buf_q1, outp, M, 256, 256);
    // 10. LN3(query2)
    ln_kernel<<<dim3(M / 4), blk, 0, stream>>>(outp, nullptr, n3s, n3b, buf_ln, M);
    // 11. FFN1 + ReLU -> h1 [7200,512]
    gemm_kernel<1><<<dim3(4, 57), blk, 0, stream>>>(buf_ln, f_w1, f_b1, nullptr, h1, M, 512, 256);
    // 12. FFN2 + residual(query2) -> d_out
    gemm_kernel<0><<<dim3(2, 57), blk, 0, stream>>>(h1, f_w2, f_b2, outp, outp, M, 256, 512);
}

// Round 2
// 1050.787 us; speedup vs baseline: 1.1728x; 1.1728x over previous
//
#include <hip/hip_runtime.h>
#include <math.h>

#define B_   8
#define NQ_  900
#define D_   256
#define H_   8
#define P_   4
#define BEV_ 200
#define FFN_ 512
#define HD_  32
#define M_   (B_*NQ_)

typedef __attribute__((ext_vector_type(8))) short short8;
typedef __attribute__((ext_vector_type(4))) float floatx4;

__device__ inline unsigned short f2bf(float f) {
    union { float f; unsigned u; } v; v.f = f;
    unsigned r = v.u + 0x7fffu + ((v.u >> 16) & 1u);
    return (unsigned short)(r >> 16);
}

// ---------------------------------------------------------------------------
// Weight fp32 -> bf16 conversion; off_w/wt_w merged into one [96,256] matrix,
// off_b/wt_b merged into one [96] fp32 bias.
// ---------------------------------------------------------------------------
__global__ __launch_bounds__(256)
void convert_weights(const float* __restrict__ in_w, const float* __restrict__ out_w,
                     const float* __restrict__ off_w, const float* __restrict__ wt_w,
                     const float* __restrict__ co_w, const float* __restrict__ f_w1,
                     const float* __restrict__ f_w2, const float* __restrict__ off_b,
                     const float* __restrict__ wt_b,
                     unsigned short* __restrict__ wb, float* __restrict__ bias_ow)
{
    int i = blockIdx.x * 256 + threadIdx.x;
    if (i < 196608)      { wb[i] = f2bf(in_w[i]); }
    else if (i < 262144) { wb[i] = f2bf(out_w[i - 196608]); }
    else if (i < 278528) { wb[i] = f2bf(off_w[i - 262144]); }
    else if (i < 286720) { wb[i] = f2bf(wt_w[i - 278528]); }
    else if (i < 352256) { wb[i] = f2bf(co_w[i - 286720]); }
    else if (i < 483328) { wb[i] = f2bf(f_w1[i - 352256]); }
    else if (i < 614400) { wb[i] = f2bf(f_w2[i - 483328]); }
    else if (i < 614464) { bias_ow[i - 614400] = off_b[i - 614400]; }
    else if (i < 614496) { bias_ow[i - 614400] = wt_b[i - 614464]; }
}

// ---------------------------------------------------------------------------
// LayerNorm over last dim (256); optional pos add. Writes bf16 (GEMM input).
// ---------------------------------------------------------------------------
__global__ __launch_bounds__(256)
void ln_kernel(const float* __restrict__ x, const float* __restrict__ pos,
               const float* __restrict__ gamma, const float* __restrict__ beta,
               unsigned short* __restrict__ out, int rows)
{
    int w    = threadIdx.x >> 6;
    int lane = threadIdx.x & 63;
    int row  = blockIdx.x * 4 + w;
    if (row >= rows) return;
    size_t base = (size_t)row * D_ + lane * 4;
    float4 v = *(const float4*)(x + base);
    if (pos) {
        float4 p = *(const float4*)(pos + base);
        v.x += p.x; v.y += p.y; v.z += p.z; v.w += p.w;
    }
    float s = v.x + v.y + v.z + v.w;
    float q = v.x*v.x + v.y*v.y + v.z*v.z + v.w*v.w;
    #pragma unroll
    for (int o = 1; o < 64; o <<= 1) {
        s += __shfl_xor(s, o, 64);
        q += __shfl_xor(q, o, 64);
    }
    float m   = s * (1.0f / D_);
    float var = q * (1.0f / D_) - m * m;
    float inv = rsqrtf(var + 1e-5f);
    float4 g = *(const float4*)(gamma + lane * 4);
    float4 b = *(const float4*)(beta  + lane * 4);
    ushort4 o4;
    o4.x = f2bf((v.x - m) * inv * g.x + b.x);
    o4.y = f2bf((v.y - m) * inv * g.y + b.y);
    o4.z = f2bf((v.z - m) * inv * g.z + b.z);
    o4.w = f2bf((v.w - m) * inv * g.w + b.w);
    *(ushort4*)(out + base) = o4;
}

// ---------------------------------------------------------------------------
// bf16 MFMA GEMM: C[m,n] = sum_k A[m,k]*W[n,k] + bias[n] (+res fp32) (relu)
// 128x128x32 tile, 256 threads = 4 waves, each wave 64x64 via 4x4 grid of
// 16x16x32 MFMA. XOR-swizzled LDS (16B chunk ^ (row&3)) for b128 reads.
// ---------------------------------------------------------------------------
template<int RELU, int OUTBF>
__global__ __launch_bounds__(256)
void gemm_mfma(const unsigned short* __restrict__ A, const unsigned short* __restrict__ W,
               const float* __restrict__ bias, const float* __restrict__ res,
               float* __restrict__ outf, unsigned short* __restrict__ outb,
               int M, int N, int K)
{
    __shared__ unsigned short As[128 * 32];
    __shared__ unsigned short Bs[128 * 32];
    const int t    = threadIdx.x;
    const int m0   = blockIdx.y * 128;
    const int n0   = blockIdx.x * 128;
    const int lane = t & 63;
    const int w    = t >> 6;
    const int wm   = (w >> 1) * 64;
    const int wn   = (w & 1) * 64;
    const int lr   = lane & 15;
    const int kq   = lane >> 4;     // 0..3

    floatx4 acc[4][4];
    #pragma unroll
    for (int i = 0; i < 4; ++i)
        #pragma unroll
        for (int j = 0; j < 4; ++j) acc[i][j] = (floatx4){0.f, 0.f, 0.f, 0.f};

    const int sr = t >> 1;          // staging row 0..127
    const int sc = (t & 1) * 2;     // 16B-chunk base: 0 or 2

    for (int k0 = 0; k0 < K; k0 += 32) {
        uint4 a0 = {0,0,0,0}, a1 = {0,0,0,0};
        int gm = m0 + sr;
        if (gm < M) {
            const uint4* src = (const uint4*)(A + (size_t)gm * K + k0 + sc * 8);
            a0 = src[0]; a1 = src[1];
        }
        *(uint4*)&As[sr * 32 + ((sc    ) ^ (sr & 3)) * 8] = a0;
        *(uint4*)&As[sr * 32 + ((sc + 1) ^ (sr & 3)) * 8] = a1;
        uint4 b0 = {0,0,0,0}, b1 = {0,0,0,0};
        int gn = n0 + sr;
        if (gn < N) {
            const uint4* src = (const uint4*)(W + (size_t)gn * K + k0 + sc * 8);
            b0 = src[0]; b1 = src[1];
        }
        *(uint4*)&Bs[sr * 32 + ((sc    ) ^ (sr & 3)) * 8] = b0;
        *(uint4*)&Bs[sr * 32 + ((sc + 1) ^ (sr & 3)) * 8] = b1;
        __syncthreads();

        short8 af[4], bf[4];
        #pragma unroll
        for (int i = 0; i < 4; ++i) {
            int ra = wm + i * 16 + lr;
            af[i] = *(const short8*)&As[ra * 32 + (kq ^ (ra & 3)) * 8];
            int rb = wn + i * 16 + lr;
            bf[i] = *(const short8*)&Bs[rb * 32 + (kq ^ (rb & 3)) * 8];
        }
        #pragma unroll
        for (int mi = 0; mi < 4; ++mi)
            #pragma unroll
            for (int ni = 0; ni < 4; ++ni)
                acc[mi][ni] = __builtin_amdgcn_mfma_f32_16x16x32_bf16(
                    af[mi], bf[ni], acc[mi][ni], 0, 0, 0);
        __syncthreads();
    }

    const int rbase = kq * 4;
    #pragma unroll
    for (int ni = 0; ni < 4; ++ni) {
        int n = n0 + wn + ni * 16 + lr;
        if (n >= N) continue;
        float bv = bias[n];
        #pragma unroll
        for (int mi = 0; mi < 4; ++mi) {
            floatx4 c = acc[mi][ni];
            #pragma unroll
            for (int r = 0; r < 4; ++r) {
                int m = m0 + wm + mi * 16 + rbase + r;
                if (m < M) {
                    float vl = c[r] + bv;
                    if (res) vl += res[(size_t)m * N + n];
                    if (RELU) vl = fmaxf(vl, 0.f);
                    if (OUTBF) outb[(size_t)m * N + n] = f2bf(vl);
                    else       outf[(size_t)m * N + n] = vl;
                }
            }
        }
    }
}

// ---------------------------------------------------------------------------
// Self-attention (unchanged from R1 except bf16 output).
// ---------------------------------------------------------------------------
__global__ __launch_bounds__(256)
void attn_kernel(const float* __restrict__ qkv, unsigned short* __restrict__ out)
{
    __shared__ float sq[4][HD_];
    __shared__ float sp[4][NQ_];
    __shared__ float sred[32][4][HD_];
    __shared__ float sinv[4];
    const int t  = threadIdx.x;
    const int b  = blockIdx.y >> 3;
    const int h  = blockIdx.y & 7;
    const int q0 = blockIdx.x * 4;

    if (t < 128) {
        int qi = t >> 5, c = t & 31;
        sq[qi][c] = qkv[((size_t)(b * NQ_ + q0 + qi)) * 768 + h * HD_ + c];
    }
    __syncthreads();
    const float scale = 0.17677669529663687f;

    for (int k = t; k < NQ_; k += 256) {
        const float* kp = qkv + ((size_t)(b * NQ_ + k)) * 768 + D_ + h * HD_;
        float4 kr[8];
        #pragma unroll
        for (int c = 0; c < 8; ++c) kr[c] = *(const float4*)(kp + c * 4);
        #pragma unroll
        for (int qi = 0; qi < 4; ++qi) {
            const float4* sv = (const float4*)sq[qi];
            float dot = 0.f;
            #pragma unroll
            for (int c = 0; c < 8; ++c) {
                float4 qv = sv[c];
                dot += qv.x*kr[c].x + qv.y*kr[c].y + qv.z*kr[c].z + qv.w*kr[c].w;
            }
            sp[qi][k] = dot * scale;
        }
    }
    __syncthreads();

    {
        int qi = t >> 6, lane = t & 63;
        float mx = -1e30f;
        for (int k = lane; k < NQ_; k += 64) mx = fmaxf(mx, sp[qi][k]);
        #pragma unroll
        for (int o = 1; o < 64; o <<= 1) mx = fmaxf(mx, __shfl_xor(mx, o, 64));
        float sum = 0.f;
        for (int k = lane; k < NQ_; k += 64) {
            float e = expf(sp[qi][k] - mx);
            sp[qi][k] = e;
            sum += e;
        }
        #pragma unroll
        for (int o = 1; o < 64; o <<= 1) sum += __shfl_xor(sum, o, 64);
        if (lane == 0) sinv[qi] = 1.f / sum;
    }
    __syncthreads();

    {
        int g  = t >> 3;
        int dg = (t & 7) * 4;
        float acc[4][4];
        #pragma unroll
        for (int qi = 0; qi < 4; ++qi)
            #pragma unroll
            for (int c = 0; c < 4; ++c) acc[qi][c] = 0.f;
        for (int k = g; k < NQ_; k += 32) {
            const float* vp = qkv + ((size_t)(b * NQ_ + k)) * 768 + 2 * D_ + h * HD_ + dg;
            float4 v = *(const float4*)vp;
            #pragma unroll
            for (int qi = 0; qi < 4; ++qi) {
                float p = sp[qi][k];
                acc[qi][0] = fmaf(p, v.x, acc[qi][0]);
                acc[qi][1] = fmaf(p, v.y, acc[qi][1]);
                acc[qi][2] = fmaf(p, v.z, acc[qi][2]);
                acc[qi][3] = fmaf(p, v.w, acc[qi][3]);
            }
        }
        #pragma unroll
        for (int qi = 0; qi < 4; ++qi)
            #pragma unroll
            for (int c = 0; c < 4; ++c) sred[g][qi][dg + c] = acc[qi][c];
    }
    __syncthreads();
    if (t < 128) {
        int qi = t >> 5, d = t & 31;
        float o = 0.f;
        #pragma unroll
        for (int g = 0; g < 32; ++g) o += sred[g][qi][d];
        out[((size_t)(b * NQ_ + q0 + qi)) * D_ + h * HD_ + d] = f2bf(o * sinv[qi]);
    }
}

// ---------------------------------------------------------------------------
// Prep: reads merged [7200,96] off|wt rows.
// ---------------------------------------------------------------------------
__global__ __launch_bounds__(256)
void prep_kernel(const float* __restrict__ offwt, const float* __restrict__ refp,
                 float4* __restrict__ sx, float4* __restrict__ sy, float4* __restrict__ sw)
{
    int idx = blockIdx.x * 256 + threadIdx.x;
    if (idx >= B_ * NQ_ * H_) return;
    int h  = idx & 7;
    int bq = idx >> 3;
    const float* orow = offwt + (size_t)bq * 96 + h * 8;
    const float* wrow = offwt + (size_t)bq * 96 + 64 + h * 4;
    float rx = refp[bq * 2 + 0];
    float ry = refp[bq * 2 + 1];
    float gx[4], gy[4], wv[4];
    #pragma unroll
    for (int p = 0; p < 4; ++p) {
        float ox = tanhf(orow[p * 2 + 0]) * 0.2f;
        float oy = tanhf(orow[p * 2 + 1]) * 0.2f;
        gx[p] = (rx + ox) * (float)BEV_ - 0.5f;
        gy[p] = (ry + oy) * (float)BEV_ - 0.5f;
        wv[p] = wrow[p];
    }
    float mx = fmaxf(fmaxf(wv[0], wv[1]), fmaxf(wv[2], wv[3]));
    float e0 = expf(wv[0]-mx), e1 = expf(wv[1]-mx), e2 = expf(wv[2]-mx), e3 = expf(wv[3]-mx);
    float inv = 1.f / (e0 + e1 + e2 + e3);
    sx[idx] = make_float4(gx[0], gx[1], gx[2], gx[3]);
    sy[idx] = make_float4(gy[0], gy[1], gy[2], gy[3]);
    sw[idx] = make_float4(e0*inv, e1*inv, e2*inv, e3*inv);
}

// ---------------------------------------------------------------------------
// Bilinear sampler; writes bf16 (feeds co-proj GEMM).
// ---------------------------------------------------------------------------
__global__ __launch_bounds__(256)
void sample_kernel(const float* __restrict__ mem,
                   const float4* __restrict__ sx, const float4* __restrict__ sy,
                   const float4* __restrict__ sw, unsigned short* __restrict__ fused)
{
    int tid = blockIdx.x * 256 + threadIdx.x;
    if (tid >= B_ * NQ_ * H_ * HD_) return;
    int d   = tid & 31;
    int bqh = tid >> 5;
    int h   = bqh & 7;
    int bq  = bqh >> 3;
    int b   = bq / NQ_;
    const float* mb = mem + (size_t)b * (BEV_ * BEV_) * D_ + h * HD_ + d;
    float4 X = sx[bqh], Y = sy[bqh], W = sw[bqh];
    float xs[4] = {X.x, X.y, X.z, X.w};
    float ys[4] = {Y.x, Y.y, Y.z, Y.w};
    float ws[4] = {W.x, W.y, W.z, W.w};
    float acc = 0.f;
    #pragma unroll
    for (int p = 0; p < 4; ++p) {
        float gx = xs[p], gy = ys[p];
        float x0f = floorf(gx), y0f = floorf(gy);
        int x0 = (int)x0f, y0 = (int)y0f;
        float wx1 = gx - x0f, wy1 = gy - y0f;
        float wx0 = 1.f - wx1, wy0 = 1.f - wy1;
        float s = 0.f;
        #pragma unroll
        for (int cy = 0; cy < 2; ++cy) {
            int yy = y0 + cy;
            if (yy < 0 || yy >= BEV_) continue;
            float wyv = cy ? wy1 : wy0;
            #pragma unroll
            for (int cx = 0; cx < 2; ++cx) {
                int xx = x0 + cx;
                if (xx < 0 || xx >= BEV_) continue;
                float wxv = cx ? wx1 : wx0;
                s += wyv * wxv * mb[((size_t)yy * BEV_ + xx) * D_];
            }
        }
        acc += ws[p] * s;
    }
    fused[(size_t)bq * D_ + h * HD_ + d] = f2bf(acc);
}

// ---------------------------------------------------------------------------
extern "C" void kernel_launch(void* const* d_in, const int* in_sizes, int n_in,
                              void* d_out, int out_size, void* d_ws, size_t ws_size,
                              hipStream_t stream) {
    const float* query     = (const float*)d_in[0];
    const float* memory    = (const float*)d_in[1];
    const float* refp      = (const float*)d_in[2];
    const float* query_pos = (const float*)d_in[3];
    const float* in_w  = (const float*)d_in[4];
    const float* in_b  = (const float*)d_in[5];
    const float* out_w = (const float*)d_in[6];
    const float* out_b = (const float*)d_in[7];
    const float* off_w = (const float*)d_in[8];
    const float* off_b = (const float*)d_in[9];
    const float* wt_w  = (const float*)d_in[10];
    const float* wt_b  = (const float*)d_in[11];
    const float* co_w  = (const float*)d_in[12];
    const float* co_b  = (const float*)d_in[13];
    const float* f_w1  = (const float*)d_in[14];
    const float* f_b1  = (const float*)d_in[15];
    const float* f_w2  = (const float*)d_in[16];
    const float* f_b2  = (const float*)d_in[17];
    const float* n1s = (const float*)d_in[18];
    const float* n1b = (const float*)d_in[19];
    const float* n2s = (const float*)d_in[20];
    const float* n2b = (const float*)d_in[21];
    const float* n3s = (const float*)d_in[22];
    const float* n3b = (const float*)d_in[23];
    float* outp = (float*)d_out;

    // workspace layout (bytes)
    char* w = (char*)d_ws;
    unsigned short* wb      = (unsigned short*)w;             // 614400 u16 = 1228800 B
    float*          bias_ow = (float*)(w + 1228800);          // 96 f32 (pad to 1229184)
    unsigned short* ln_bf   = (unsigned short*)(w + 1229184); // 7200*256 u16 = 3686400 B
    float*          q1      = (float*)(w + 4915584);          // 7200*256 f32 = 7372800 B
    char*           big     = w + 12288384;                   // 22118400 B region
    float*          qkv     = (float*)big;                    // 7200*768 f32
    float*          offwt   = (float*)big;                    // 7200*96 f32 (after attn)
    float*          samp    = (float*)(big + 2764800);        // 3*57600 float4 = 2764800 B
    unsigned short* fuse_bf = (unsigned short*)(big + 5529600);// 7200*256 u16
    unsigned short* h1_bf   = (unsigned short*)big;           // 7200*512 u16 (after co-proj)
    unsigned short* attn_bf = ln_bf;                          // reuse (dead between LN uses)

    const unsigned short* wb_in  = wb;
    const unsigned short* wb_out = wb + 196608;
    const unsigned short* wb_ow  = wb + 262144;  // merged [96,256]
    const unsigned short* wb_co  = wb + 286720;
    const unsigned short* wb_f1  = wb + 352256;
    const unsigned short* wb_f2  = wb + 483328;

    dim3 blk(256);
    const int M = M_;

    // 0. weights -> bf16 (+ merged off/wt bias)
    convert_weights<<<dim3((614496 + 255) / 256), blk, 0, stream>>>(
        in_w, out_w, off_w, wt_w, co_w, f_w1, f_w2, off_b, wt_b, wb, bias_ow);
    // 1. LN1(query + pos) -> bf16
    ln_kernel<<<dim3(M / 4), blk, 0, stream>>>(query, query_pos, n1s, n1b, ln_bf, M);
    // 2. QKV [7200,768] fp32
    gemm_mfma<0,0><<<dim3(6, 57), blk, 0, stream>>>(ln_bf, wb_in, in_b, nullptr,
                                                    qkv, nullptr, M, 768, 256);
    // 3. self-attention -> bf16 [7200,256]
    attn_kernel<<<dim3(225, B_ * H_), blk, 0, stream>>>(qkv, attn_bf);
    // 4. out-proj + residual(query) -> q1 fp32
    gemm_mfma<0,0><<<dim3(2, 57), blk, 0, stream>>>(attn_bf, wb_out, out_b, query,
                                                    q1, nullptr, M, 256, 256);
    // 5. LN2(q1 + pos) -> bf16
    ln_kernel<<<dim3(M / 4), blk, 0, stream>>>(q1, query_pos, n2s, n2b, ln_bf, M);
    // 6. merged off|wt projection [7200,96] fp32
    gemm_mfma<0,0><<<dim3(1, 57), blk, 0, stream>>>(ln_bf, wb_ow, bias_ow, nullptr,
                                                    offwt, nullptr, M, 96, 256);
    // 7. sampling coords + P-softmax
    prep_kernel<<<dim3((B_ * NQ_ * H_ + 255) / 256), blk, 0, stream>>>(
        offwt, refp, (float4*)samp, (float4*)samp + 57600, (float4*)samp + 115200);
    // 8. bilinear sample + fuse -> bf16
    sample_kernel<<<dim3(B_ * NQ_ * H_ * HD_ / 256), blk, 0, stream>>>(
        memory, (const float4*)samp, (const float4*)samp + 57600,
        (const float4*)samp + 115200, fuse_bf);
    // 9. co-proj + residual(q1) -> d_out fp32
    gemm_mfma<0,0><<<dim3(2, 57), blk, 0, stream>>>(fuse_bf, wb_co, co_b, q1,
                                                    outp, nullptr, M, 256, 256);
    // 10. LN3(d_out) -> bf16
    ln_kernel<<<dim3(M / 4), blk, 0, stream>>>(outp, nullptr, n3s, n3b, ln_bf, M);
    // 11. FFN1 + ReLU -> bf16 h1 [7200,512]
    gemm_mfma<1,1><<<dim3(4, 57), blk, 0, stream>>>(ln_bf, wb_f1, f_b1, nullptr,
                                                    nullptr, h1_bf, M, 512, 256);
    // 12. FFN2 + residual(d_out) -> d_out fp32
    gemm_mfma<0,0><<<dim3(2, 57), blk, 0, stream>>>(h1_bf, wb_f2, f_b2, outp,
                                                    outp, nullptr, M, 256, 512);
}

// Round 3
// 674.397 us; speedup vs baseline: 1.8274x; 1.5581x over previous
//
#include <hip/hip_runtime.h>
#include <math.h>

#define B_   8
#define NQ_  900
#define D_   256
#define H_   8
#define P_   4
#define BEV_ 200
#define FFN_ 512
#define HD_  32
#define M_   (B_*NQ_)
#define NKPAD 960

typedef __attribute__((ext_vector_type(8))) short short8;
typedef __attribute__((ext_vector_type(4))) float floatx4;

__device__ inline unsigned short f2bf(float f) {
    union { float f; unsigned u; } v; v.f = f;
    unsigned r = v.u + 0x7fffu + ((v.u >> 16) & 1u);
    return (unsigned short)(r >> 16);
}
__device__ inline float bf2f(unsigned short h) {
    union { unsigned u; float f; } v; v.u = ((unsigned)h) << 16;
    return v.f;
}

// ---------------------------------------------------------------------------
// Weight fp32 -> bf16; off_w/wt_w merged into [96,256]; off_b/wt_b -> [96].
// ---------------------------------------------------------------------------
__global__ __launch_bounds__(256)
void convert_weights(const float* __restrict__ in_w, const float* __restrict__ out_w,
                     const float* __restrict__ off_w, const float* __restrict__ wt_w,
                     const float* __restrict__ co_w, const float* __restrict__ f_w1,
                     const float* __restrict__ f_w2, const float* __restrict__ off_b,
                     const float* __restrict__ wt_b,
                     unsigned short* __restrict__ wb, float* __restrict__ bias_ow)
{
    int i = blockIdx.x * 256 + threadIdx.x;
    if (i < 196608)      { wb[i] = f2bf(in_w[i]); }
    else if (i < 262144) { wb[i] = f2bf(out_w[i - 196608]); }
    else if (i < 278528) { wb[i] = f2bf(off_w[i - 262144]); }
    else if (i < 286720) { wb[i] = f2bf(wt_w[i - 278528]); }
    else if (i < 352256) { wb[i] = f2bf(co_w[i - 286720]); }
    else if (i < 483328) { wb[i] = f2bf(f_w1[i - 352256]); }
    else if (i < 614400) { wb[i] = f2bf(f_w2[i - 483328]); }
    else if (i < 614464) { bias_ow[i - 614400] = off_b[i - 614400]; }
    else if (i < 614496) { bias_ow[i - 614400] = wt_b[i - 614464]; }
}

// ---------------------------------------------------------------------------
// LayerNorm over last dim (256); optional pos add; bf16 out.
// ---------------------------------------------------------------------------
__global__ __launch_bounds__(256)
void ln_kernel(const float* __restrict__ x, const float* __restrict__ pos,
               const float* __restrict__ gamma, const float* __restrict__ beta,
               unsigned short* __restrict__ out, int rows)
{
    int w    = threadIdx.x >> 6;
    int lane = threadIdx.x & 63;
    int row  = blockIdx.x * 4 + w;
    if (row >= rows) return;
    size_t base = (size_t)row * D_ + lane * 4;
    float4 v = *(const float4*)(x + base);
    if (pos) {
        float4 p = *(const float4*)(pos + base);
        v.x += p.x; v.y += p.y; v.z += p.z; v.w += p.w;
    }
    float s = v.x + v.y + v.z + v.w;
    float q = v.x*v.x + v.y*v.y + v.z*v.z + v.w*v.w;
    #pragma unroll
    for (int o = 1; o < 64; o <<= 1) {
        s += __shfl_xor(s, o, 64);
        q += __shfl_xor(q, o, 64);
    }
    float m   = s * (1.0f / D_);
    float var = q * (1.0f / D_) - m * m;
    float inv = rsqrtf(var + 1e-5f);
    float4 g = *(const float4*)(gamma + lane * 4);
    float4 b = *(const float4*)(beta  + lane * 4);
    ushort4 o4;
    o4.x = f2bf((v.x - m) * inv * g.x + b.x);
    o4.y = f2bf((v.y - m) * inv * g.y + b.y);
    o4.z = f2bf((v.z - m) * inv * g.z + b.z);
    o4.w = f2bf((v.w - m) * inv * g.w + b.w);
    *(ushort4*)(out + base) = o4;
}

// ---------------------------------------------------------------------------
// bf16 MFMA GEMM (unchanged from R2).
// ---------------------------------------------------------------------------
template<int RELU, int OUTBF>
__global__ __launch_bounds__(256)
void gemm_mfma(const unsigned short* __restrict__ A, const unsigned short* __restrict__ W,
               const float* __restrict__ bias, const float* __restrict__ res,
               float* __restrict__ outf, unsigned short* __restrict__ outb,
               int M, int N, int K)
{
    __shared__ unsigned short As[128 * 32];
    __shared__ unsigned short Bs[128 * 32];
    const int t    = threadIdx.x;
    const int m0   = blockIdx.y * 128;
    const int n0   = blockIdx.x * 128;
    const int lane = t & 63;
    const int w    = t >> 6;
    const int wm   = (w >> 1) * 64;
    const int wn   = (w & 1) * 64;
    const int lr   = lane & 15;
    const int kq   = lane >> 4;

    floatx4 acc[4][4];
    #pragma unroll
    for (int i = 0; i < 4; ++i)
        #pragma unroll
        for (int j = 0; j < 4; ++j) acc[i][j] = (floatx4){0.f, 0.f, 0.f, 0.f};

    const int sr = t >> 1;
    const int sc = (t & 1) * 2;

    for (int k0 = 0; k0 < K; k0 += 32) {
        uint4 a0 = {0,0,0,0}, a1 = {0,0,0,0};
        int gm = m0 + sr;
        if (gm < M) {
            const uint4* src = (const uint4*)(A + (size_t)gm * K + k0 + sc * 8);
            a0 = src[0]; a1 = src[1];
        }
        *(uint4*)&As[sr * 32 + ((sc    ) ^ (sr & 3)) * 8] = a0;
        *(uint4*)&As[sr * 32 + ((sc + 1) ^ (sr & 3)) * 8] = a1;
        uint4 b0 = {0,0,0,0}, b1 = {0,0,0,0};
        int gn = n0 + sr;
        if (gn < N) {
            const uint4* src = (const uint4*)(W + (size_t)gn * K + k0 + sc * 8);
            b0 = src[0]; b1 = src[1];
        }
        *(uint4*)&Bs[sr * 32 + ((sc    ) ^ (sr & 3)) * 8] = b0;
        *(uint4*)&Bs[sr * 32 + ((sc + 1) ^ (sr & 3)) * 8] = b1;
        __syncthreads();

        short8 af[4], bfr[4];
        #pragma unroll
        for (int i = 0; i < 4; ++i) {
            int ra = wm + i * 16 + lr;
            af[i] = *(const short8*)&As[ra * 32 + (kq ^ (ra & 3)) * 8];
            int rb = wn + i * 16 + lr;
            bfr[i] = *(const short8*)&Bs[rb * 32 + (kq ^ (rb & 3)) * 8];
        }
        #pragma unroll
        for (int mi = 0; mi < 4; ++mi)
            #pragma unroll
            for (int ni = 0; ni < 4; ++ni)
                acc[mi][ni] = __builtin_amdgcn_mfma_f32_16x16x32_bf16(
                    af[mi], bfr[ni], acc[mi][ni], 0, 0, 0);
        __syncthreads();
    }

    const int rbase = kq * 4;
    #pragma unroll
    for (int ni = 0; ni < 4; ++ni) {
        int n = n0 + wn + ni * 16 + lr;
        if (n >= N) continue;
        float bv = bias[n];
        #pragma unroll
        for (int mi = 0; mi < 4; ++mi) {
            floatx4 c = acc[mi][ni];
            #pragma unroll
            for (int r = 0; r < 4; ++r) {
                int m = m0 + wm + mi * 16 + rbase + r;
                if (m < M) {
                    float vl = c[r] + bv;
                    if (res) vl += res[(size_t)m * N + n];
                    if (RELU) vl = fmaxf(vl, 0.f);
                    if (OUTBF) outb[(size_t)m * N + n] = f2bf(vl);
                    else       outf[(size_t)m * N + n] = vl;
                }
            }
        }
    }
}

// ---------------------------------------------------------------------------
// Repack bf16 qkv [7200,768] into flash layouts:
//   Qb[bh][960][32] (pre-scaled by 1/sqrt(32)), Kb[bh][960][32], Vt[bh][32][960]
// Zero-fill rows >= 900.
// ---------------------------------------------------------------------------
__global__ __launch_bounds__(256)
void repack_qkv(const unsigned short* __restrict__ qkv,
                unsigned short* __restrict__ Qb, unsigned short* __restrict__ Kb,
                unsigned short* __restrict__ Vt)
{
    int tid = blockIdx.x * 256 + threadIdx.x;
    if (tid >= 64 * NKPAD * 32) return;
    int ch  = tid & 31;
    int key = (tid >> 5) % NKPAD;
    int bh  = tid / (NKPAD * 32);
    int b = bh >> 3, h = bh & 7;
    unsigned short qv = 0, kv = 0, vv = 0;
    if (key < NQ_) {
        const unsigned short* row = qkv + ((size_t)(b * NQ_ + key)) * 768 + h * 32 + ch;
        qv = f2bf(bf2f(row[0]) * 0.17677669529663687f);
        kv = row[256];
        vv = row[512];
    }
    size_t qk_idx = (size_t)bh * NKPAD * 32 + key * 32 + ch;
    Qb[qk_idx] = qv;
    Kb[qk_idx] = kv;
    Vt[(size_t)(bh * 32 + ch) * NKPAD + key] = vv;
}

// ---------------------------------------------------------------------------
// Flash self-attention. Grid (15, 64). 4 waves/block; wave owns 16 q-rows.
// Online softmax fully in registers; P transposed via per-wave LDS.
// ---------------------------------------------------------------------------
__global__ __launch_bounds__(256)
void flash_attn(const unsigned short* __restrict__ Qb, const unsigned short* __restrict__ Kb,
                const unsigned short* __restrict__ Vt, unsigned short* __restrict__ out)
{
    __shared__ unsigned short P_lds[4][16][72];
    const int bh   = blockIdx.y;
    const int b    = bh >> 3, h = bh & 7;
    const int q0   = blockIdx.x * 64;
    const int w    = threadIdx.x >> 6;
    const int lane = threadIdx.x & 63;
    const int lr   = lane & 15;
    const int quad = lane >> 4;

    // Q A-fragment: A[m=lr][k=quad*8..+8], loaded once (pre-scaled).
    const short8 qfrag = *(const short8*)(Qb + ((size_t)bh * NKPAD + q0 + w * 16 + lr) * 32 + quad * 8);

    floatx4 O0 = (floatx4){0.f,0.f,0.f,0.f};
    floatx4 O1 = (floatx4){0.f,0.f,0.f,0.f};
    float m_i[4] = {-INFINITY, -INFINITY, -INFINITY, -INFINITY};
    float l_i[4] = {0.f, 0.f, 0.f, 0.f};

    const unsigned short* kbase_p = Kb + (size_t)bh * NKPAD * 32;
    const unsigned short* vbase_p = Vt + (size_t)bh * 32 * NKPAD;

    for (int kt = 0; kt < 15; ++kt) {
        const int kb = kt * 64;
        // --- QK^T: 4 MFMAs -> S[16q x 64keys] ---
        short8 kf[4];
        #pragma unroll
        for (int ni = 0; ni < 4; ++ni)
            kf[ni] = *(const short8*)(kbase_p + (size_t)(kb + ni * 16 + lr) * 32 + quad * 8);
        floatx4 S[4];
        #pragma unroll
        for (int ni = 0; ni < 4; ++ni)
            S[ni] = __builtin_amdgcn_mfma_f32_16x16x32_bf16(
                qfrag, kf[ni], (floatx4){0.f,0.f,0.f,0.f}, 0, 0, 0);
        // --- mask tail keys ---
        if (kt == 14) {
            #pragma unroll
            for (int ni = 0; ni < 4; ++ni) {
                int key = kb + ni * 16 + lr;
                if (key >= NQ_) S[ni] = (floatx4){-1e30f, -1e30f, -1e30f, -1e30f};
            }
        }
        // --- online softmax (row = quad*4 + r for both S and O) ---
        float rowmax[4];
        #pragma unroll
        for (int r = 0; r < 4; ++r)
            rowmax[r] = fmaxf(fmaxf(S[0][r], S[1][r]), fmaxf(S[2][r], S[3][r]));
        #pragma unroll
        for (int off = 1; off < 16; off <<= 1)
            #pragma unroll
            for (int r = 0; r < 4; ++r)
                rowmax[r] = fmaxf(rowmax[r], __shfl_xor(rowmax[r], off, 64));
        float alpha[4], rs[4];
        #pragma unroll
        for (int r = 0; r < 4; ++r) {
            float mnew = fmaxf(m_i[r], rowmax[r]);
            alpha[r] = __expf(m_i[r] - mnew);
            m_i[r] = mnew;
            rs[r] = 0.f;
        }
        #pragma unroll
        for (int ni = 0; ni < 4; ++ni) {
            #pragma unroll
            for (int r = 0; r < 4; ++r) {
                float p = __expf(S[ni][r] - m_i[r]);
                rs[r] += p;
                P_lds[w][quad * 4 + r][ni * 16 + lr] = f2bf(p);
            }
        }
        #pragma unroll
        for (int off = 1; off < 16; off <<= 1)
            #pragma unroll
            for (int r = 0; r < 4; ++r)
                rs[r] += __shfl_xor(rs[r], off, 64);
        #pragma unroll
        for (int r = 0; r < 4; ++r) {
            l_i[r] = alpha[r] * l_i[r] + rs[r];
            O0[r] *= alpha[r];
            O1[r] *= alpha[r];
        }
        // wave-internal LDS RAW: drain ds_writes before ds_reads
        asm volatile("s_waitcnt lgkmcnt(0)" ::: "memory");
        // --- P A-fragments + V^T B-fragments -> PV ---
        short8 pf0 = *(const short8*)&P_lds[w][lr][quad * 8];
        short8 pf1 = *(const short8*)&P_lds[w][lr][32 + quad * 8];
        short8 vf;
        vf = *(const short8*)(vbase_p + (size_t)(lr) * NKPAD + kb + quad * 8);
        O0 = __builtin_amdgcn_mfma_f32_16x16x32_bf16(pf0, vf, O0, 0, 0, 0);
        vf = *(const short8*)(vbase_p + (size_t)(lr) * NKPAD + kb + 32 + quad * 8);
        O0 = __builtin_amdgcn_mfma_f32_16x16x32_bf16(pf1, vf, O0, 0, 0, 0);
        vf = *(const short8*)(vbase_p + (size_t)(16 + lr) * NKPAD + kb + quad * 8);
        O1 = __builtin_amdgcn_mfma_f32_16x16x32_bf16(pf0, vf, O1, 0, 0, 0);
        vf = *(const short8*)(vbase_p + (size_t)(16 + lr) * NKPAD + kb + 32 + quad * 8);
        O1 = __builtin_amdgcn_mfma_f32_16x16x32_bf16(pf1, vf, O1, 0, 0, 0);
        // ensure LDS reads done before next iteration overwrites P
        asm volatile("s_waitcnt lgkmcnt(0)" ::: "memory");
    }
    // --- epilogue: out[b*900+q][h*32+d] ---
    #pragma unroll
    for (int r = 0; r < 4; ++r) {
        int q = q0 + w * 16 + quad * 4 + r;
        if (q < NQ_) {
            float inv = 1.f / l_i[r];
            size_t base = ((size_t)(b * NQ_ + q)) * D_ + h * 32;
            out[base + lr]      = f2bf(O0[r] * inv);
            out[base + 16 + lr] = f2bf(O1[r] * inv);
        }
    }
}

// ---------------------------------------------------------------------------
// Prep: reads merged [7200,96] off|wt rows.
// ---------------------------------------------------------------------------
__global__ __launch_bounds__(256)
void prep_kernel(const float* __restrict__ offwt, const float* __restrict__ refp,
                 float4* __restrict__ sx, float4* __restrict__ sy, float4* __restrict__ sw)
{
    int idx = blockIdx.x * 256 + threadIdx.x;
    if (idx >= B_ * NQ_ * H_) return;
    int h  = idx & 7;
    int bq = idx >> 3;
    const float* orow = offwt + (size_t)bq * 96 + h * 8;
    const float* wrow = offwt + (size_t)bq * 96 + 64 + h * 4;
    float rx = refp[bq * 2 + 0];
    float ry = refp[bq * 2 + 1];
    float gx[4], gy[4], wv[4];
    #pragma unroll
    for (int p = 0; p < 4; ++p) {
        float ox = tanhf(orow[p * 2 + 0]) * 0.2f;
        float oy = tanhf(orow[p * 2 + 1]) * 0.2f;
        gx[p] = (rx + ox) * (float)BEV_ - 0.5f;
        gy[p] = (ry + oy) * (float)BEV_ - 0.5f;
        wv[p] = wrow[p];
    }
    float mx = fmaxf(fmaxf(wv[0], wv[1]), fmaxf(wv[2], wv[3]));
    float e0 = expf(wv[0]-mx), e1 = expf(wv[1]-mx), e2 = expf(wv[2]-mx), e3 = expf(wv[3]-mx);
    float inv = 1.f / (e0 + e1 + e2 + e3);
    sx[idx] = make_float4(gx[0], gx[1], gx[2], gx[3]);
    sy[idx] = make_float4(gy[0], gy[1], gy[2], gy[3]);
    sw[idx] = make_float4(e0*inv, e1*inv, e2*inv, e3*inv);
}

// ---------------------------------------------------------------------------
// Bilinear sampler; bf16 out.
// ---------------------------------------------------------------------------
__global__ __launch_bounds__(256)
void sample_kernel(const float* __restrict__ mem,
                   const float4* __restrict__ sx, const float4* __restrict__ sy,
                   const float4* __restrict__ sw, unsigned short* __restrict__ fused)
{
    int tid = blockIdx.x * 256 + threadIdx.x;
    if (tid >= B_ * NQ_ * H_ * HD_) return;
    int d   = tid & 31;
    int bqh = tid >> 5;
    int h   = bqh & 7;
    int bq  = bqh >> 3;
    int b   = bq / NQ_;
    const float* mb = mem + (size_t)b * (BEV_ * BEV_) * D_ + h * HD_ + d;
    float4 X = sx[bqh], Y = sy[bqh], W = sw[bqh];
    float xs[4] = {X.x, X.y, X.z, X.w};
    float ys[4] = {Y.x, Y.y, Y.z, Y.w};
    float ws[4] = {W.x, W.y, W.z, W.w};
    float acc = 0.f;
    #pragma unroll
    for (int p = 0; p < 4; ++p) {
        float gx = xs[p], gy = ys[p];
        float x0f = floorf(gx), y0f = floorf(gy);
        int x0 = (int)x0f, y0 = (int)y0f;
        float wx1 = gx - x0f, wy1 = gy - y0f;
        float wx0 = 1.f - wx1, wy0 = 1.f - wy1;
        float s = 0.f;
        #pragma unroll
        for (int cy = 0; cy < 2; ++cy) {
            int yy = y0 + cy;
            if (yy < 0 || yy >= BEV_) continue;
            float wyv = cy ? wy1 : wy0;
            #pragma unroll
            for (int cx = 0; cx < 2; ++cx) {
                int xx = x0 + cx;
                if (xx < 0 || xx >= BEV_) continue;
                float wxv = cx ? wx1 : wx0;
                s += wyv * wxv * mb[((size_t)yy * BEV_ + xx) * D_];
            }
        }
        acc += ws[p] * s;
    }
    fused[(size_t)bq * D_ + h * HD_ + d] = f2bf(acc);
}

// ---------------------------------------------------------------------------
extern "C" void kernel_launch(void* const* d_in, const int* in_sizes, int n_in,
                              void* d_out, int out_size, void* d_ws, size_t ws_size,
                              hipStream_t stream) {
    const float* query     = (const float*)d_in[0];
    const float* memory    = (const float*)d_in[1];
    const float* refp      = (const float*)d_in[2];
    const float* query_pos = (const float*)d_in[3];
    const float* in_w  = (const float*)d_in[4];
    const float* in_b  = (const float*)d_in[5];
    const float* out_w = (const float*)d_in[6];
    const float* out_b = (const float*)d_in[7];
    const float* off_w = (const float*)d_in[8];
    const float* off_b = (const float*)d_in[9];
    const float* wt_w  = (const float*)d_in[10];
    const float* wt_b  = (const float*)d_in[11];
    const float* co_w  = (const float*)d_in[12];
    const float* co_b  = (const float*)d_in[13];
    const float* f_w1  = (const float*)d_in[14];
    const float* f_b1  = (const float*)d_in[15];
    const float* f_w2  = (const float*)d_in[16];
    const float* f_b2  = (const float*)d_in[17];
    const float* n1s = (const float*)d_in[18];
    const float* n1b = (const float*)d_in[19];
    const float* n2s = (const float*)d_in[20];
    const float* n2b = (const float*)d_in[21];
    const float* n3s = (const float*)d_in[22];
    const float* n3b = (const float*)d_in[23];
    float* outp = (float*)d_out;

    // workspace layout (bytes)
    char* w = (char*)d_ws;
    unsigned short* wb      = (unsigned short*)w;              // 1,228,800
    float*          bias_ow = (float*)(w + 1228800);           // 384 (pad)
    unsigned short* ln_bf   = (unsigned short*)(w + 1229184);  // 3,686,400
    float*          q1      = (float*)(w + 4915584);           // 7,372,800
    unsigned short* qkv_bf  = (unsigned short*)(w + 12288384); // 11,059,200
    unsigned short* Qb      = (unsigned short*)(w + 23347584); // 3,932,160
    unsigned short* Kb      = (unsigned short*)(w + 27279744); // 3,932,160
    unsigned short* Vt      = (unsigned short*)(w + 31211904); // 3,932,160 -> end 35,144,064
    // overlays on dead qkv_bf region:
    float*          offwt   = (float*)(w + 12288384);          // 2,764,800
    float*          samp    = (float*)(w + 15053184);          // 2,764,800
    unsigned short* fuse_bf = (unsigned short*)(w + 17817984); // 3,686,400
    unsigned short* h1_bf   = (unsigned short*)(w + 12288384); // 7,372,800 (after fuse consumed)
    unsigned short* attn_bf = ln_bf;                           // reuse

    const unsigned short* wb_in  = wb;
    const unsigned short* wb_out = wb + 196608;
    const unsigned short* wb_ow  = wb + 262144;
    const unsigned short* wb_co  = wb + 286720;
    const unsigned short* wb_f1  = wb + 352256;
    const unsigned short* wb_f2  = wb + 483328;

    dim3 blk(256);
    const int M = M_;

    // 0. weights -> bf16
    convert_weights<<<dim3((614496 + 255) / 256), blk, 0, stream>>>(
        in_w, out_w, off_w, wt_w, co_w, f_w1, f_w2, off_b, wt_b, wb, bias_ow);
    // 1. LN1(query + pos) -> bf16
    ln_kernel<<<dim3(M / 4), blk, 0, stream>>>(query, query_pos, n1s, n1b, ln_bf, M);
    // 2. QKV [7200,768] -> bf16
    gemm_mfma<0,1><<<dim3(6, 57), blk, 0, stream>>>(ln_bf, wb_in, in_b, nullptr,
                                                    nullptr, qkv_bf, M, 768, 256);
    // 3. repack into flash layouts
    repack_qkv<<<dim3(64 * NKPAD * 32 / 256), blk, 0, stream>>>(qkv_bf, Qb, Kb, Vt);
    // 4. flash attention -> bf16
    flash_attn<<<dim3(15, 64), blk, 0, stream>>>(Qb, Kb, Vt, attn_bf);
    // 5. out-proj + residual(query) -> q1 fp32
    gemm_mfma<0,0><<<dim3(2, 57), blk, 0, stream>>>(attn_bf, wb_out, out_b, query,
                                                    q1, nullptr, M, 256, 256);
    // 6. LN2(q1 + pos) -> bf16
    ln_kernel<<<dim3(M / 4), blk, 0, stream>>>(q1, query_pos, n2s, n2b, ln_bf, M);
    // 7. merged off|wt projection [7200,96]
    gemm_mfma<0,0><<<dim3(1, 57), blk, 0, stream>>>(ln_bf, wb_ow, bias_ow, nullptr,
                                                    offwt, nullptr, M, 96, 256);
    // 8. sampling coords + P-softmax
    prep_kernel<<<dim3((B_ * NQ_ * H_ + 255) / 256), blk, 0, stream>>>(
        offwt, refp, (float4*)samp, (float4*)samp + 57600, (float4*)samp + 115200);
    // 9. bilinear sample + fuse -> bf16
    sample_kernel<<<dim3(B_ * NQ_ * H_ * HD_ / 256), blk, 0, stream>>>(
        memory, (const float4*)samp, (const float4*)samp + 57600,
        (const float4*)samp + 115200, fuse_bf);
    // 10. co-proj + residual(q1) -> d_out fp32
    gemm_mfma<0,0><<<dim3(2, 57), blk, 0, stream>>>(fuse_bf, wb_co, co_b, q1,
                                                    outp, nullptr, M, 256, 256);
    // 11. LN3(d_out) -> bf16
    ln_kernel<<<dim3(M / 4), blk, 0, stream>>>(outp, nullptr, n3s, n3b, ln_bf, M);
    // 12. FFN1 + ReLU -> bf16 h1
    gemm_mfma<1,1><<<dim3(4, 57), blk, 0, stream>>>(ln_bf, wb_f1, f_b1, nullptr,
                                                    nullptr, h1_bf, M, 512, 256);
    // 13. FFN2 + residual(d_out) -> d_out
    gemm_mfma<0,0><<<dim3(2, 57), blk, 0, stream>>>(h1_bf, wb_f2, f_b2, outp,
                                                    outp, nullptr, M, 256, 512);
}